// Round 9
// baseline (206.745 us; speedup 1.0000x reference)
//
#include <hip/hip_runtime.h>
#include <math.h>

#define BN_ 16
#define SS  2048
#define HH  1024
#define AA  64

typedef unsigned short u16;
typedef __bf16 bf16x8 __attribute__((ext_vector_type(8)));
typedef float  f32x4  __attribute__((ext_vector_type(4)));
#define MFMA16 __builtin_amdgcn_mfma_f32_16x16x32_bf16

// ---------------- ws layout (float offsets) ----------------
#define QK_OFF    0
#define QK_FLOATS (BN_*SS*64)           // bf16 qk[32768][128]: Q cols 0..63, K cols 64..127
#define WT_OFF    (QK_OFF + QK_FLOATS)  // bf16 wt[128][1024] (WqT||WkT)
#define WT_FLOATS (64*HH)
#define CP_OFF    (WT_OFF + WT_FLOATS)  // cpart[16][32][2][2048] fp32 (strip col partials)
#define CP_FLOATS (BN_*32*2*SS)
#define W_OFF     (CP_OFF + CP_FLOATS)  // w[b][t]
#define NB_OFF    (W_OFF + BN_*SS)      // Nb per batch [16]
#define NBW_OFF   (NB_OFF + 16)         // Nb/(Nb+1e-8) per batch [16]
#define UP_OFF    (NBW_OFF + 16)        // u_part[16][32][1024] fp32

__device__ __forceinline__ u16 f2b(float f) {
    unsigned u = __builtin_bit_cast(unsigned, f);
    return (u16)((u + 0x7FFFu + ((u >> 16) & 1u)) >> 16);
}

__device__ __forceinline__ bf16x8 cvt8(float4 a, float4 b) {
    bf16x8 r;
    r[0] = (__bf16)a.x; r[1] = (__bf16)a.y; r[2] = (__bf16)a.z; r[3] = (__bf16)a.w;
    r[4] = (__bf16)b.x; r[5] = (__bf16)b.y; r[6] = (__bf16)b.z; r[7] = (__bf16)b.w;
    return r;
}

// swizzled elem index in a [rows][64] bf16 LDS tile (row stride 128B)
__device__ __forceinline__ int swze(int row, int e) {
    return row * 64 + (e ^ ((row & 7) << 3));
}

// MFMA A/B fragment from swizzled tile: rows row16..row16+15, k-step ks
__device__ __forceinline__ bf16x8 ldfrag(const u16* t, int row16, int ks, int l6) {
    int row = row16 + (l6 & 15);
    int e = ks * 32 + ((l6 >> 4) << 3);
    return *(const bf16x8*)&t[swze(row, e)];
}

// ---- A: transpose Wq||Wk -> bf16 wt[128][1024] ----
__global__ __launch_bounds__(256) void k_wt(const float* __restrict__ Wq,
                                            const float* __restrict__ Wk,
                                            u16* __restrict__ wt) {
    int n = blockIdx.x;
    const float* src = (n < 64) ? &Wq[n] : &Wk[n - 64];
    for (int k = threadIdx.x; k < HH; k += 256)
        wt[(size_t)n * HH + k] = f2b(src[(size_t)k * AA]);
}

// ---- B: QK projection; B(wt) dbuf LDS, A reg-direct pipelined 1 kt ahead ----
// grid 512 (2 blocks/CU); block = 64 rows; wave = 16 rows.
__global__ __launch_bounds__(256) void k_qkproj(const float* __restrict__ x,
                                                const u16* __restrict__ wt,
                                                const float* __restrict__ bq,
                                                const float* __restrict__ bk,
                                                u16* __restrict__ qk) {
    __shared__ __align__(16) u16 Bs0[128 * 64];
    __shared__ __align__(16) u16 Bs1[128 * 64];
    int tid = threadIdx.x, l6 = tid & 63, w = tid >> 6;
    int lr = l6 & 15, lk = l6 >> 4;
    int row = blockIdx.x * 64 + w * 16;
    const float* xr = x + (size_t)(row + lr) * HH + lk * 8;
    int sr = tid >> 3, sc = (tid & 7) * 8;     // sr 0..31, sc 0..56
    const u16* bsrc = wt + (size_t)sr * HH + sc;
    uint4 g0, g1, g2, g3;
    float4 x0, x1, x2, x3;
    #define LOADB(kt) { const u16* p_ = bsrc + (kt) * 64;                         \
        g0 = *(const uint4*)p_;              g1 = *(const uint4*)(p_ + 32 * HH);  \
        g2 = *(const uint4*)(p_ + 64 * HH);  g3 = *(const uint4*)(p_ + 96 * HH); }
    #define WRITEB(B_) { *(uint4*)&B_[swze(sr, sc)] = g0;      *(uint4*)&B_[swze(sr + 32, sc)] = g1; \
        *(uint4*)&B_[swze(sr + 64, sc)] = g2; *(uint4*)&B_[swze(sr + 96, sc)] = g3; }
    #define LOADA(kt) { const float* p_ = xr + (kt) * 64;                          \
        x0 = *(const float4*)p_;        x1 = *(const float4*)(p_ + 4);             \
        x2 = *(const float4*)(p_ + 32); x3 = *(const float4*)(p_ + 36); }

    f32x4 acc[8];
    #pragma unroll
    for (int j = 0; j < 8; ++j) acc[j] = (f32x4){0.f, 0.f, 0.f, 0.f};

    LOADB(0); WRITEB(Bs0); LOADA(0);
    __syncthreads();
    for (int kt = 0; kt < 16; ++kt) {
        const u16* Bs = (kt & 1) ? Bs1 : Bs0;
        bf16x8 a0 = cvt8(x0, x1);              // waits on A(kt)
        bf16x8 a1 = cvt8(x2, x3);
        if (kt < 15) { LOADB(kt + 1); LOADA(kt + 1); }   // in flight under MFMA+LDS
        #pragma unroll
        for (int j = 0; j < 8; ++j) {
            bf16x8 b0 = ldfrag(Bs, j * 16, 0, l6);
            bf16x8 b1 = ldfrag(Bs, j * 16, 1, l6);
            acc[j] = MFMA16(a0, b0, acc[j], 0, 0, 0);
            acc[j] = MFMA16(a1, b1, acc[j], 0, 0, 0);
        }
        if (kt < 15) {
            if (kt & 1) { WRITEB(Bs0); } else { WRITEB(Bs1); }   // other buffer
            __syncthreads();
        }
    }
    #pragma unroll
    for (int j = 0; j < 8; ++j) {
        int n = j * 16 + lr;
        float bias = (n < 64) ? bq[n] : bk[n - 64];
        int mrow = row + lk * 4;
        #pragma unroll
        for (int r4 = 0; r4 < 4; ++r4)
            qk[(size_t)(mrow + r4) * 128 + n] = f2b(acc[j][r4] + bias);
    }
    #undef LOADB
    #undef WRITEB
    #undef LOADA
}

// ---- E: Nb per batch (+ analytic sum-of-w) ----
__global__ __launch_bounds__(256) void k_nb(const int* __restrict__ mask,
                                            float* __restrict__ nbv,
                                            float* __restrict__ nbw) {
    int b = blockIdx.x, tid = threadIdx.x;
    int s = 0;
    for (int i = tid; i < SS; i += 256) s += mask[b * SS + i];
    float fs = (float)s;
    for (int off = 1; off < 64; off <<= 1) fs += __shfl_xor(fs, off);
    __shared__ float red[4];
    if ((tid & 63) == 0) red[tid >> 6] = fs;
    __syncthreads();
    if (tid == 0) {
        float t = red[0] + red[1] + red[2] + red[3];
        nbv[b] = t + 1e-8f;
        nbw[b] = t / (t + 1e-8f);
    }
}

// ---- C+D fused: Q strip 64 rows; dbuf Ks; additive mask + ln(1/l) fold ----
__global__ __launch_bounds__(256) void k_score(const u16* __restrict__ qk,
                                               const int* __restrict__ mask,
                                               float* __restrict__ cpart) {
    __shared__ __align__(16) u16 Ks0[128 * 64];
    __shared__ __align__(16) u16 Ks1[128 * 64];
    __shared__ float pml[SS];            // additive key mask: 0 or -1e30
    __shared__ float colacc[2][128];
    int bid = blockIdx.x;
    int b = bid >> 5, sb = bid & 31;
    int tid = threadIdx.x, l6 = tid & 63, w = tid >> 6;
    int lr = l6 & 15, lk = l6 >> 4;
    for (int i = tid; i < SS; i += 256) pml[i] = mask[b * SS + i] ? 0.f : -1e30f;
    const u16* qkb = qk + (size_t)b * SS * 128;
    const u16* qp = qkb + (size_t)(sb * 64 + w * 16 + lr) * 128 + lk * 8;
    bf16x8 q0 = *(const bf16x8*)qp;
    bf16x8 q1 = *(const bf16x8*)(qp + 32);
    int sr = tid >> 3, sc = (tid & 7) * 8;
    const u16* ksrc = qkb + 64 + (size_t)sr * 128 + sc;
    uint4 g0, g1, g2, g3;
    #define LOADK(tt) { const u16* p_ = ksrc + (size_t)(tt) * 128 * 128;              \
        g0 = *(const uint4*)p_;              g1 = *(const uint4*)(p_ + 32 * 128);     \
        g2 = *(const uint4*)(p_ + 64 * 128); g3 = *(const uint4*)(p_ + 96 * 128); }
    #define WRITEK(B_) { *(uint4*)&B_[swze(sr, sc)] = g0;      *(uint4*)&B_[swze(sr + 32, sc)] = g1; \
        *(uint4*)&B_[swze(sr + 64, sc)] = g2; *(uint4*)&B_[swze(sr + 96, sc)] = g3; }

    LOADK(0);
    __syncthreads();                 // pml visible
    const f32x4 vz = {0.f, 0.f, 0.f, 0.f};
    // ---- pass 1: row sums l (masked exp) ----
    float rsum[4] = {0.f, 0.f, 0.f, 0.f};
    for (int tt = 0; tt < 16; ++tt) {
        u16* Ks = (tt & 1) ? Ks1 : Ks0;
        WRITEK(Ks);
        __syncthreads();
        if (tt < 15) LOADK(tt + 1);
        #pragma unroll
        for (int j = 0; j < 8; ++j) {
            bf16x8 k0 = ldfrag(Ks, j * 16, 0, l6);
            bf16x8 k1 = ldfrag(Ks, j * 16, 1, l6);
            f32x4 a = vz;
            a = MFMA16(q0, k0, a, 0, 0, 0);
            a = MFMA16(q1, k1, a, 0, 0, 0);
            float pmv = pml[tt * 128 + j * 16 + lr];
            #pragma unroll
            for (int r4 = 0; r4 < 4; ++r4)
                rsum[r4] += __expf(fmaf(a[r4], 0.125f, pmv));
        }
        // no trailing sync: dbuf — next tt writes the other buffer
    }
    #pragma unroll
    for (int off = 1; off < 16; off <<= 1)
        #pragma unroll
        for (int r4 = 0; r4 < 4; ++r4)
            rsum[r4] += __shfl_xor(rsum[r4], off);
    float lsh[4], qm4[4];
    #pragma unroll
    for (int r4 = 0; r4 < 4; ++r4) {
        float lv = rsum[r4];
        lsh[r4] = (lv > 0.f) ? -__logf(lv) : -1e30f;
        int srow = sb * 64 + w * 16 + lk * 4 + r4;
        qm4[r4] = (pml[srow] == 0.f) ? 1.f : 0.f;
    }
    // ---- pass 2: column partials via LDS-atomic accumulators ----
    LOADK(0);
    ((float*)colacc)[tid] = 0.f;     // 256 entries = one per thread
    __syncthreads();                 // covers pass1 reads of both Ks bufs + zeroing
    for (int tt = 0; tt < 16; ++tt) {
        u16* Ks = (tt & 1) ? Ks1 : Ks0;
        WRITEK(Ks);
        __syncthreads();
        if (tt < 15) LOADK(tt + 1);
        #pragma unroll
        for (int j = 0; j < 8; ++j) {
            bf16x8 k0 = ldfrag(Ks, j * 16, 0, l6);
            bf16x8 k1 = ldfrag(Ks, j * 16, 1, l6);
            f32x4 a = vz;
            a = MFMA16(q0, k0, a, 0, 0, 0);
            a = MFMA16(q1, k1, a, 0, 0, 0);
            float pmv = pml[tt * 128 + j * 16 + lr];
            float sa = 0.f, sm = 0.f;
            #pragma unroll
            for (int r4 = 0; r4 < 4; ++r4) {
                float e = __expf(fmaf(a[r4], 0.125f, lsh[r4]) + pmv);
                sa += e;
                sm = fmaf(qm4[r4], e, sm);
            }
            sa += __shfl_xor(sa, 16); sa += __shfl_xor(sa, 32);
            sm += __shfl_xor(sm, 16); sm += __shfl_xor(sm, 32);
            if (lk == 0) {
                atomicAdd(&colacc[0][j * 16 + lr], sa);
                atomicAdd(&colacc[1][j * 16 + lr], sm);
            }
        }
        __syncthreads();             // all adds done
        {
            int a2 = tid >> 7, tl = tid & 127;
            float s = colacc[a2][tl];
            cpart[(((size_t)b * 32 + sb) * 2 + a2) * SS + tt * 128 + tl] = s;
            colacc[a2][tl] = 0.f;    // next tt's adds come after next sync
        }
    }
    #undef LOADK
    #undef WRITEK
}

// ---- F: reduce col partials -> attn_mean, w ----
__global__ __launch_bounds__(256) void k_finalize(const float* __restrict__ cpart,
                                                  const int* __restrict__ mask,
                                                  const float* __restrict__ nbv,
                                                  float* __restrict__ w,
                                                  float* __restrict__ out_mean) {
    int b = blockIdx.x, tb = blockIdx.y, tid = threadIdx.x;
    int t = tb * 256 + tid;
    float inv_nb = 1.f / nbv[b];
    float sa = 0.f, sm = 0.f;
    #pragma unroll 8
    for (int k = 0; k < 32; ++k) {
        const float* p = &cpart[(((size_t)b * 32 + k) * 2) * SS + t];
        sa += p[0];
        sm += p[SS];
    }
    float pm = mask[b * SS + t] ? 1.f : 0.f;
    out_mean[b * SS + t] = sa * pm * (1.f / SS);
    w[b * SS + t] = sm * pm * inv_nb;
}

// ---- G: u partials: u_part[b][ch][c] = sum_{t in chunk} w[t]*x[t][c] ----
__global__ __launch_bounds__(256) void k_u(const float* __restrict__ x,
                                           const float* __restrict__ w,
                                           float* __restrict__ u_part) {
    __shared__ float wl[64];
    int b = blockIdx.x, ch = blockIdx.y;   // ch 0..31, 64 t each
    int tid = threadIdx.x;
    if (tid < 64) wl[tid] = w[b * SS + ch * 64 + tid];
    __syncthreads();
    const float* xb = &x[((size_t)b * SS + ch * 64) * HH + tid * 4];
    float4 acc = {0.f, 0.f, 0.f, 0.f};
    #pragma unroll 16
    for (int t = 0; t < 64; ++t) {
        float4 xv = *(const float4*)&xb[(size_t)t * HH];
        float wv = wl[t];
        acc.x += wv * xv.x; acc.y += wv * xv.y;
        acc.z += wv * xv.z; acc.w += wv * xv.w;
    }
    *(float4*)&u_part[((size_t)b * 32 + ch) * HH + tid * 4] = acc;
}

// ---- H: out0[b][h] = sum_c u[b][c]*Wv[c][h] + bv[h]*nbw[b] ----
__global__ __launch_bounds__(256) void k_out0(const float* __restrict__ u_part,
                                              const float* __restrict__ Wv,
                                              const float* __restrict__ bv,
                                              const float* __restrict__ nbw,
                                              float* __restrict__ out) {
    __shared__ float us[HH];
    int b = blockIdx.x, hb = blockIdx.y;
    int tid = threadIdx.x;
    float4 s = {0.f, 0.f, 0.f, 0.f};
    #pragma unroll 8
    for (int ch = 0; ch < 32; ++ch) {
        float4 v = *(const float4*)&u_part[((size_t)b * 32 + ch) * HH + tid * 4];
        s.x += v.x; s.y += v.y; s.z += v.z; s.w += v.w;
    }
    *(float4*)&us[tid * 4] = s;
    __syncthreads();
    int h = hb * 256 + tid;
    float acc = bv[h] * nbw[b];
    #pragma unroll 8
    for (int c = 0; c < HH; ++c)
        acc += us[c] * Wv[(size_t)c * HH + h];
    out[b * HH + h] = acc;
}

extern "C" void kernel_launch(void* const* d_in, const int* in_sizes, int n_in,
                              void* d_out, int out_size, void* d_ws, size_t ws_size,
                              hipStream_t stream) {
    const float* x  = (const float*)d_in[0];
    const int* mask = (const int*)d_in[1];
    const float* Wq = (const float*)d_in[2];
    const float* bq = (const float*)d_in[3];
    const float* Wk = (const float*)d_in[4];
    const float* bk = (const float*)d_in[5];
    const float* Wv = (const float*)d_in[6];
    const float* bv = (const float*)d_in[7];
    float* out = (float*)d_out;
    float* ws  = (float*)d_ws;

    u16*   qk    = (u16*)(ws + QK_OFF);
    u16*   wt    = (u16*)(ws + WT_OFF);
    float* cpart = ws + CP_OFF;
    float* w     = ws + W_OFF;
    float* nbv   = ws + NB_OFF;
    float* nbw   = ws + NBW_OFF;
    float* upart = ws + UP_OFF;

    k_wt      <<<dim3(128),     dim3(256), 0, stream>>>(Wq, Wk, wt);
    k_qkproj  <<<dim3(512),     dim3(256), 0, stream>>>(x, wt, bq, bk, qk);
    k_nb      <<<dim3(BN_),     dim3(256), 0, stream>>>(mask, nbv, nbw);
    k_score   <<<dim3(512),     dim3(256), 0, stream>>>(qk, mask, cpart);
    k_finalize<<<dim3(BN_, 8),  dim3(256), 0, stream>>>(cpart, mask, nbv, w, out + BN_ * HH);
    k_u       <<<dim3(BN_, 32), dim3(256), 0, stream>>>(x, w, upart);
    k_out0    <<<dim3(BN_, 4),  dim3(256), 0, stream>>>(upart, Wv, bv, nbw, out);
}

// Round 10
// 164.646 us; speedup vs baseline: 1.2557x; 1.2557x over previous
//
#include <hip/hip_runtime.h>
#include <math.h>

#define BN_ 16
#define SS  2048
#define HH  1024
#define AA  64

typedef unsigned short u16;
typedef __bf16 bf16x8 __attribute__((ext_vector_type(8)));
typedef float  f32x4  __attribute__((ext_vector_type(4)));
typedef float  f32x16 __attribute__((ext_vector_type(16)));
#define MFMA16 __builtin_amdgcn_mfma_f32_16x16x32_bf16
#define MFMA32 __builtin_amdgcn_mfma_f32_32x32x16_bf16

// ---------------- ws layout (float offsets) ----------------
#define QK_OFF    0
#define QK_FLOATS (BN_*SS*64)           // bf16 qk[32768][128]: Q cols 0..63, K cols 64..127
#define WT_OFF    (QK_OFF + QK_FLOATS)  // bf16 wt[128][1024] (WqT||WkT)
#define WT_FLOATS (64*HH)
#define CP_OFF    (WT_OFF + WT_FLOATS)  // cpart[16][32][2][2048] fp32 (strip col partials)
#define CP_FLOATS (BN_*32*2*SS)
#define W_OFF     (CP_OFF + CP_FLOATS)  // w[b][t]
#define NB_OFF    (W_OFF + BN_*SS)      // Nb per batch [16]
#define NBW_OFF   (NB_OFF + 16)         // Nb/(Nb+1e-8) per batch [16]
#define UP_OFF    (NBW_OFF + 16)        // u_part[16][32][1024] fp32

__device__ __forceinline__ u16 f2b(float f) {
    unsigned u = __builtin_bit_cast(unsigned, f);
    return (u16)((u + 0x7FFFu + ((u >> 16) & 1u)) >> 16);
}

__device__ __forceinline__ bf16x8 cvt8(float4 a, float4 b) {
    bf16x8 r;
    r[0] = (__bf16)a.x; r[1] = (__bf16)a.y; r[2] = (__bf16)a.z; r[3] = (__bf16)a.w;
    r[4] = (__bf16)b.x; r[5] = (__bf16)b.y; r[6] = (__bf16)b.z; r[7] = (__bf16)b.w;
    return r;
}

// swizzled elem index in a [rows][64] bf16 LDS tile (row stride 128B)
__device__ __forceinline__ int swze(int row, int e) {
    return row * 64 + (e ^ ((row & 7) << 3));
}

// MFMA16 A/B fragment from swizzled tile
__device__ __forceinline__ bf16x8 ldfrag(const u16* t, int row16, int ks, int l6) {
    int row = row16 + (l6 & 15);
    int e = ks * 32 + ((l6 >> 4) << 3);
    return *(const bf16x8*)&t[swze(row, e)];
}

// ---- A: transpose Wq||Wk -> bf16 wt[128][1024] ----
__global__ __launch_bounds__(256) void k_wt(const float* __restrict__ Wq,
                                            const float* __restrict__ Wk,
                                            u16* __restrict__ wt) {
    int n = blockIdx.x;
    const float* src = (n < 64) ? &Wq[n] : &Wk[n - 64];
    for (int k = threadIdx.x; k < HH; k += 256)
        wt[(size_t)n * HH + k] = f2b(src[(size_t)k * AA]);
}

// ---- B: QK projection; B(wt) dbuf LDS, A reg-direct pipelined 1 kt ahead ----
__global__ __launch_bounds__(256) void k_qkproj(const float* __restrict__ x,
                                                const u16* __restrict__ wt,
                                                const float* __restrict__ bq,
                                                const float* __restrict__ bk,
                                                u16* __restrict__ qk) {
    __shared__ __align__(16) u16 Bs0[128 * 64];
    __shared__ __align__(16) u16 Bs1[128 * 64];
    int tid = threadIdx.x, l6 = tid & 63, w = tid >> 6;
    int lr = l6 & 15, lk = l6 >> 4;
    int row = blockIdx.x * 64 + w * 16;
    const float* xr = x + (size_t)(row + lr) * HH + lk * 8;
    int sr = tid >> 3, sc = (tid & 7) * 8;
    const u16* bsrc = wt + (size_t)sr * HH + sc;
    uint4 g0, g1, g2, g3;
    float4 x0, x1, x2, x3;
    #define LOADB(kt) { const u16* p_ = bsrc + (kt) * 64;                         \
        g0 = *(const uint4*)p_;              g1 = *(const uint4*)(p_ + 32 * HH);  \
        g2 = *(const uint4*)(p_ + 64 * HH);  g3 = *(const uint4*)(p_ + 96 * HH); }
    #define WRITEB(B_) { *(uint4*)&B_[swze(sr, sc)] = g0;      *(uint4*)&B_[swze(sr + 32, sc)] = g1; \
        *(uint4*)&B_[swze(sr + 64, sc)] = g2; *(uint4*)&B_[swze(sr + 96, sc)] = g3; }
    #define LOADA(kt) { const float* p_ = xr + (kt) * 64;                          \
        x0 = *(const float4*)p_;        x1 = *(const float4*)(p_ + 4);             \
        x2 = *(const float4*)(p_ + 32); x3 = *(const float4*)(p_ + 36); }

    f32x4 acc[8];
    #pragma unroll
    for (int j = 0; j < 8; ++j) acc[j] = (f32x4){0.f, 0.f, 0.f, 0.f};

    LOADB(0); WRITEB(Bs0); LOADA(0);
    __syncthreads();
    for (int kt = 0; kt < 16; ++kt) {
        const u16* Bs = (kt & 1) ? Bs1 : Bs0;
        bf16x8 a0 = cvt8(x0, x1);
        bf16x8 a1 = cvt8(x2, x3);
        if (kt < 15) { LOADB(kt + 1); LOADA(kt + 1); }
        #pragma unroll
        for (int j = 0; j < 8; ++j) {
            bf16x8 b0 = ldfrag(Bs, j * 16, 0, l6);
            bf16x8 b1 = ldfrag(Bs, j * 16, 1, l6);
            acc[j] = MFMA16(a0, b0, acc[j], 0, 0, 0);
            acc[j] = MFMA16(a1, b1, acc[j], 0, 0, 0);
        }
        if (kt < 15) {
            if (kt & 1) { WRITEB(Bs0); } else { WRITEB(Bs1); }
            __syncthreads();
        }
    }
    #pragma unroll
    for (int j = 0; j < 8; ++j) {
        int n = j * 16 + lr;
        float bias = (n < 64) ? bq[n] : bk[n - 64];
        int mrow = row + lk * 4;
        #pragma unroll
        for (int r4 = 0; r4 < 4; ++r4)
            qk[(size_t)(mrow + r4) * 128 + n] = f2b(acc[j][r4] + bias);
    }
    #undef LOADB
    #undef WRITEB
    #undef LOADA
}

// ---- E: Nb per batch (+ analytic sum-of-w) ----
__global__ __launch_bounds__(256) void k_nb(const int* __restrict__ mask,
                                            float* __restrict__ nbv,
                                            float* __restrict__ nbw) {
    int b = blockIdx.x, tid = threadIdx.x;
    int s = 0;
    for (int i = tid; i < SS; i += 256) s += mask[b * SS + i];
    float fs = (float)s;
    for (int off = 1; off < 64; off <<= 1) fs += __shfl_xor(fs, off);
    __shared__ float red[4];
    if ((tid & 63) == 0) red[tid >> 6] = fs;
    __syncthreads();
    if (tid == 0) {
        float t = red[0] + red[1] + red[2] + red[3];
        nbv[b] = t + 1e-8f;
        nbw[b] = t / (t + 1e-8f);
    }
}

// ---- C+D fused, 32x32 MFMA: strip = 64 q-rows; wave w owns cols w*32..+31 ----
// acc layout (m74/m101): col = lane&31, row = (reg&3) + 8*(reg>>2) + 4*(lane>>5)
__global__ __launch_bounds__(256) void k_score(const u16* __restrict__ qk,
                                               const int* __restrict__ mask,
                                               float* __restrict__ cpart) {
    __shared__ __align__(16) u16 Ks0[128 * 64];
    __shared__ __align__(16) u16 Ks1[128 * 64];
    __shared__ float pml[SS];          // additive key mask: 0 or -1e30
    __shared__ float redbuf[4][64];
    __shared__ float lshs[64];
    int bid = blockIdx.x;
    int b = bid >> 5, sb = bid & 31;
    int tid = threadIdx.x, l6 = tid & 63, w = tid >> 6;
    int cl = l6 & 31, hi = l6 >> 5;
    for (int i = tid; i < SS; i += 256) pml[i] = mask[b * SS + i] ? 0.f : -1e30f;
    const u16* qkb = qk + (size_t)b * SS * 128;
    int q0 = sb * 64;
    // Q A-frags (global, reg-resident): lane holds row q0+rs*32+cl, k = ks*16+hi*8..+7
    bf16x8 qA[2][4];
    #pragma unroll
    for (int rs = 0; rs < 2; ++rs)
        #pragma unroll
        for (int ks = 0; ks < 4; ++ks)
            qA[rs][ks] = *(const bf16x8*)&qkb[(size_t)(q0 + rs * 32 + cl) * 128 + ks * 16 + hi * 8];
    // K staging: 128x64 tile, 256 thr x 4 uint4
    int sr = tid >> 3, sc = (tid & 7) * 8;
    const u16* ksrc = qkb + 64 + (size_t)sr * 128 + sc;
    uint4 g0, g1, g2, g3;
    #define LOADK(tt) { const u16* p_ = ksrc + (size_t)(tt) * 128 * 128;              \
        g0 = *(const uint4*)p_;              g1 = *(const uint4*)(p_ + 32 * 128);     \
        g2 = *(const uint4*)(p_ + 64 * 128); g3 = *(const uint4*)(p_ + 96 * 128); }
    #define WRITEK(B_) { *(uint4*)&B_[swze(sr, sc)] = g0;      *(uint4*)&B_[swze(sr + 32, sc)] = g1; \
        *(uint4*)&B_[swze(sr + 64, sc)] = g2; *(uint4*)&B_[swze(sr + 96, sc)] = g3; }

    LOADK(0);
    __syncthreads();                   // pml visible
    // ---- pass 1: row sums of masked exp (each wave: its 32 cols, all 64 rows) ----
    float rsum[2][16];
    #pragma unroll
    for (int rs = 0; rs < 2; ++rs)
        #pragma unroll
        for (int r = 0; r < 16; ++r) rsum[rs][r] = 0.f;
    for (int tt = 0; tt < 16; ++tt) {
        u16* Ks = (tt & 1) ? Ks1 : Ks0;
        WRITEK(Ks);
        __syncthreads();
        if (tt < 15) LOADK(tt + 1);
        bf16x8 kB[4];
        #pragma unroll
        for (int ks = 0; ks < 4; ++ks)
            kB[ks] = *(const bf16x8*)&Ks[swze(w * 32 + cl, ks * 16 + hi * 8)];
        float pmv = pml[tt * 128 + w * 32 + cl];
        #pragma unroll
        for (int rs = 0; rs < 2; ++rs) {
            f32x16 acc = {};
            #pragma unroll
            for (int ks = 0; ks < 4; ++ks) acc = MFMA32(qA[rs][ks], kB[ks], acc, 0, 0, 0);
            #pragma unroll
            for (int r = 0; r < 16; ++r)
                rsum[rs][r] += __expf(fmaf(acc[r], 0.125f, pmv));
        }
    }
    // reduce over this wave's 32 cols (low 5 lane bits)
    #pragma unroll
    for (int off = 1; off < 32; off <<= 1)
        #pragma unroll
        for (int rs = 0; rs < 2; ++rs)
            #pragma unroll
            for (int r = 0; r < 16; ++r)
                rsum[rs][r] += __shfl_xor(rsum[rs][r], off);
    // cross-wave combine (one-time): redbuf[w][row]
    if (cl == 0) {
        #pragma unroll
        for (int rs = 0; rs < 2; ++rs)
            #pragma unroll
            for (int r = 0; r < 16; ++r)
                redbuf[w][rs * 32 + (r & 3) + 8 * (r >> 2) + 4 * hi] = rsum[rs][r];
    }
    LOADK(0);                          // prefetch pass-2 tile 0 under the combine
    __syncthreads();
    if (tid < 64) {
        float lv = redbuf[0][tid] + redbuf[1][tid] + redbuf[2][tid] + redbuf[3][tid];
        lshs[tid] = (lv > 0.f) ? -__logf(lv) : -1e30f;
    }
    __syncthreads();
    // per-lane lsh regs + q-row mask bitmask
    float lsh[2][16];
    unsigned qmb = 0;
    #pragma unroll
    for (int rs = 0; rs < 2; ++rs)
        #pragma unroll
        for (int r = 0; r < 16; ++r) {
            int rowi = rs * 32 + (r & 3) + 8 * (r >> 2) + 4 * hi;
            lsh[rs][r] = lshs[rowi];
            qmb |= (pml[q0 + rowi] == 0.f ? 1u : 0u) << (rs * 16 + r);
        }
    // ---- pass 2: column sums (wave-local: in-reg over rows + shfl(32)) ----
    for (int tt = 0; tt < 16; ++tt) {
        u16* Ks = (tt & 1) ? Ks1 : Ks0;
        WRITEK(Ks);
        __syncthreads();
        if (tt < 15) LOADK(tt + 1);
        bf16x8 kB[4];
        #pragma unroll
        for (int ks = 0; ks < 4; ++ks)
            kB[ks] = *(const bf16x8*)&Ks[swze(w * 32 + cl, ks * 16 + hi * 8)];
        float pmv = pml[tt * 128 + w * 32 + cl];
        float sa = 0.f, sm = 0.f;
        #pragma unroll
        for (int rs = 0; rs < 2; ++rs) {
            f32x16 acc = {};
            #pragma unroll
            for (int ks = 0; ks < 4; ++ks) acc = MFMA32(qA[rs][ks], kB[ks], acc, 0, 0, 0);
            #pragma unroll
            for (int r = 0; r < 16; ++r) {
                float e = __expf(fmaf(acc[r], 0.125f, lsh[rs][r]) + pmv);
                sa += e;
                sm += ((qmb >> (rs * 16 + r)) & 1u) ? e : 0.f;
            }
        }
        sa += __shfl_xor(sa, 32);      // fold hi half (rows 4..7 mod 8 live there)
        sm += __shfl_xor(sm, 32);
        if (hi == 0) {
            size_t base = (((size_t)b * 32 + sb) * 2) * SS + tt * 128 + w * 32 + cl;
            cpart[base] = sa;
            cpart[base + SS] = sm;
        }
    }
    #undef LOADK
    #undef WRITEK
}

// ---- F: reduce col partials -> attn_mean, w ----
__global__ __launch_bounds__(256) void k_finalize(const float* __restrict__ cpart,
                                                  const int* __restrict__ mask,
                                                  const float* __restrict__ nbv,
                                                  float* __restrict__ w,
                                                  float* __restrict__ out_mean) {
    int b = blockIdx.x, tb = blockIdx.y, tid = threadIdx.x;
    int t = tb * 256 + tid;
    float inv_nb = 1.f / nbv[b];
    float sa = 0.f, sm = 0.f;
    #pragma unroll 8
    for (int k = 0; k < 32; ++k) {
        const float* p = &cpart[(((size_t)b * 32 + k) * 2) * SS + t];
        sa += p[0];
        sm += p[SS];
    }
    float pm = mask[b * SS + t] ? 1.f : 0.f;
    out_mean[b * SS + t] = sa * pm * (1.f / SS);
    w[b * SS + t] = sm * pm * inv_nb;
}

// ---- G: u partials: u_part[b][ch][c] = sum_{t in chunk} w[t]*x[t][c] ----
__global__ __launch_bounds__(256) void k_u(const float* __restrict__ x,
                                           const float* __restrict__ w,
                                           float* __restrict__ u_part) {
    __shared__ float wl[64];
    int b = blockIdx.x, ch = blockIdx.y;
    int tid = threadIdx.x;
    if (tid < 64) wl[tid] = w[b * SS + ch * 64 + tid];
    __syncthreads();
    const float* xb = &x[((size_t)b * SS + ch * 64) * HH + tid * 4];
    float4 acc = {0.f, 0.f, 0.f, 0.f};
    #pragma unroll 16
    for (int t = 0; t < 64; ++t) {
        float4 xv = *(const float4*)&xb[(size_t)t * HH];
        float wv = wl[t];
        acc.x += wv * xv.x; acc.y += wv * xv.y;
        acc.z += wv * xv.z; acc.w += wv * xv.w;
    }
    *(float4*)&u_part[((size_t)b * 32 + ch) * HH + tid * 4] = acc;
}

// ---- H: out0[b][h] = sum_c u[b][c]*Wv[c][h] + bv[h]*nbw[b] ----
__global__ __launch_bounds__(256) void k_out0(const float* __restrict__ u_part,
                                              const float* __restrict__ Wv,
                                              const float* __restrict__ bv,
                                              const float* __restrict__ nbw,
                                              float* __restrict__ out) {
    __shared__ float us[HH];
    int b = blockIdx.x, hb = blockIdx.y;
    int tid = threadIdx.x;
    float4 s = {0.f, 0.f, 0.f, 0.f};
    #pragma unroll 8
    for (int ch = 0; ch < 32; ++ch) {
        float4 v = *(const float4*)&u_part[((size_t)b * 32 + ch) * HH + tid * 4];
        s.x += v.x; s.y += v.y; s.z += v.z; s.w += v.w;
    }
    *(float4*)&us[tid * 4] = s;
    __syncthreads();
    int h = hb * 256 + tid;
    float acc = bv[h] * nbw[b];
    #pragma unroll 8
    for (int c = 0; c < HH; ++c)
        acc += us[c] * Wv[(size_t)c * HH + h];
    out[b * HH + h] = acc;
}

extern "C" void kernel_launch(void* const* d_in, const int* in_sizes, int n_in,
                              void* d_out, int out_size, void* d_ws, size_t ws_size,
                              hipStream_t stream) {
    const float* x  = (const float*)d_in[0];
    const int* mask = (const int*)d_in[1];
    const float* Wq = (const float*)d_in[2];
    const float* bq = (const float*)d_in[3];
    const float* Wk = (const float*)d_in[4];
    const float* bk = (const float*)d_in[5];
    const float* Wv = (const float*)d_in[6];
    const float* bv = (const float*)d_in[7];
    float* out = (float*)d_out;
    float* ws  = (float*)d_ws;

    u16*   qk    = (u16*)(ws + QK_OFF);
    u16*   wt    = (u16*)(ws + WT_OFF);
    float* cpart = ws + CP_OFF;
    float* w     = ws + W_OFF;
    float* nbv   = ws + NB_OFF;
    float* nbw   = ws + NBW_OFF;
    float* upart = ws + UP_OFF;

    k_wt      <<<dim3(128),     dim3(256), 0, stream>>>(Wq, Wk, wt);
    k_nb      <<<dim3(BN_),     dim3(256), 0, stream>>>(mask, nbv, nbw);
    k_qkproj  <<<dim3(512),     dim3(256), 0, stream>>>(x, wt, bq, bk, qk);
    k_score   <<<dim3(512),     dim3(256), 0, stream>>>(qk, mask, cpart);
    k_finalize<<<dim3(BN_, 8),  dim3(256), 0, stream>>>(cpart, mask, nbv, w, out + BN_ * HH);
    k_u       <<<dim3(BN_, 32), dim3(256), 0, stream>>>(x, w, upart);
    k_out0    <<<dim3(BN_, 4),  dim3(256), 0, stream>>>(upart, Wv, bv, nbw, out);
}